// Round 6
// baseline (126.407 us; speedup 1.0000x reference)
//
#include <hip/hip_runtime.h>
#include <hip/hip_fp16.h>

// ---------------------------------------------------------------------------
// B=8, N=1024, F=320, H=5 (heads collapse: at = (Q·K^T)/8)
// R21 (bisect): fused_attn reverted EXACTLY to R19 (passed, 44.9us);
//   g1_combined -> g1_wave kept from R20: one 64x64x320 tile per WAVE,
//   1920 independent waves, wave-private LDS dbuf, counted vmcnt, zero
//   barriers (same wave-autonomous pattern as R19's passed fused loops).
//   If this fails, the R20 bug is isolated to g1_wave; if it passes, the
//   bug was in the R20 fused deepening.
// Pipeline: prep_all -> g1_wave (hWT + Q/K) -> fused_attn.
// ---------------------------------------------------------------------------

typedef __attribute__((ext_vector_type(8))) _Float16 half8;
typedef __attribute__((ext_vector_type(4))) float f32x4;

#define WAITV(N) do { asm volatile("s_waitcnt vmcnt(" #N ")" ::: "memory"); \
                      __builtin_amdgcn_sched_barrier(0); } while (0)

// ---- wave-private stage: one wave stages nrow16*16 rows x 32 halfs --------
// LDS slot s of row r holds global 8-half chunk s ^ ((r>>1)&3); matches the
// read-side swz = (quad ^ ((lrow>>1)&3))*8. Dest is uniform base + lane*16B.
__device__ __forceinline__ void stage_wave(const __half* g, __half* lds,
                                           int nrow16, int ld, int lane) {
    const int r = lane >> 2;
    const int c = ((lane & 3) ^ ((lane >> 3) & 3)) * 8;  // swizzled chunk
    for (int i = 0; i < nrow16; ++i) {
        const __half* src = g + (long)(i * 16 + r) * ld + c;
        __builtin_amdgcn_global_load_lds(
            (const __attribute__((address_space(1))) unsigned int*)src,
            (__attribute__((address_space(3))) unsigned int*)(lds + i * 512),
            16, 0, 0);
    }
}

// ---- fused prep: h->fp16 (blocks 0..2559) | Wqk^T | weight^T --------------
__global__ __launch_bounds__(256) void prep_all(
    const float* __restrict__ h, ushort4* __restrict__ h16,
    const float* __restrict__ Wqk, __half* __restrict__ WqkT,
    const float* __restrict__ weight, __half* __restrict__ wTp)
{
    const int bx = blockIdx.x;
    if (bx < 2560) {
        const int i = bx * 256 + threadIdx.x;
        const float4 v = ((const float4*)h)[i];
        ushort4 o;
        o.x = __half_as_ushort(__float2half(v.x));
        o.y = __half_as_ushort(__float2half(v.y));
        o.z = __half_as_ushort(__float2half(v.z));
        o.w = __half_as_ushort(__float2half(v.w));
        h16[i] = o;
        return;
    }
    __shared__ float t[32][33];
    const float* src;
    __half* dst;
    int ldS, ldT, c0, r0;
    if (bx < 2760) {
        const int b = bx - 2560;
        src = Wqk; dst = WqkT; ldS = 640; ldT = 320;
        c0 = (b % 20) * 32; r0 = (b / 20) * 32;
    } else {
        const int b = bx - 2760;
        src = weight; dst = wTp; ldS = 320; ldT = 320;
        c0 = (b % 10) * 32; r0 = (b / 10) * 32;
    }
    const int lx = threadIdx.x & 31, ly = threadIdx.x >> 5;
    #pragma unroll
    for (int i = 0; i < 4; ++i)
        t[ly + 8 * i][lx] = src[(long)(r0 + ly + 8 * i) * ldS + c0 + lx];
    __syncthreads();
    #pragma unroll
    for (int i = 0; i < 4; ++i)
        dst[(long)(c0 + ly + 8 * i) * ldT + r0 + lx] = __float2half(t[lx][ly + 8 * i]);
}

// ---------------------------------------------------------------------------
// g1_wave: one 64x64x320 NT fp16 GEMM tile per WAVE. 480 blocks x 4 waves =
// 1920 tiles: 640 hWT tiles (320x8192 = 5x128) then 1280 G1' tiles
// (8192x640 = 128x10). Wave-private LDS (A dbuf 2x2048 + B dbuf 2x2048
// halfs = 16KB), global_load_lds + counted vmcnt(8). NO barriers at all.
// EPI hWT: fp16 store ld 8192. EPI G1': +bqk, deinterleave -> Q,K fp16.
// ---------------------------------------------------------------------------
__global__ __launch_bounds__(256) void g1_wave(
    const __half* __restrict__ h16, const __half* __restrict__ wTp,
    const __half* __restrict__ WqkT, __half* __restrict__ hWT,
    __half* __restrict__ Qo, __half* __restrict__ Ko,
    const float* __restrict__ bqk)
{
    __shared__ __half smem[32768];   // 4 waves x 8192 halfs (64 KB)
    const int tid  = threadIdx.x;
    const int lane = tid & 63;
    const int wave = tid >> 6;
    const int lrow = lane & 15;
    const int quad = lane >> 4;
    const int swz  = (quad ^ ((lrow >> 1) & 3)) * 8;

    __half* const ab = smem + wave * 8192;          // A dbuf: 2 x 2048
    __half* const bb = smem + wave * 8192 + 4096;   // B dbuf: 2 x 2048

    const int gid = blockIdx.x * 4 + wave;          // 0..1919
    const __half *Aw, *Bw;
    int row_base, col_base, epi;
    if (gid < 640) {            // hWT = wTp @ h16^T  (M=320, N=8192)
        const int m = gid % 5, n = gid / 5;
        Aw = wTp + (long)m * 64 * 320;
        Bw = h16 + (long)n * 64 * 320;
        row_base = m * 64; col_base = n * 64; epi = 2;
    } else {                    // [Q|K] = h16 @ WqkT^T + bqk (M=8192, N=640)
        const int g2 = gid - 640;
        const int r = g2 % 128, c = g2 / 128;
        Aw = h16  + (long)r * 64 * 320;
        Bw = WqkT + (long)c * 64 * 320;
        row_base = r * 64; col_base = c * 64; epi = 1;
    }

    f32x4 acc[4][4];
    #pragma unroll
    for (int i = 0; i < 4; ++i)
        #pragma unroll
        for (int j = 0; j < 4; ++j) acc[i][j] = (f32x4){0.f, 0.f, 0.f, 0.f};

    // prologue: chunk 0 (8 loads)
    stage_wave(Aw, ab, 4, 320, lane);
    stage_wave(Bw, bb, 4, 320, lane);

    #pragma unroll
    for (int kc = 0; kc < 10; ++kc) {
        if (kc < 9) {
            stage_wave(Aw + (kc + 1) * 32, ab + ((kc + 1) & 1) * 2048, 4, 320, lane);
            stage_wave(Bw + (kc + 1) * 32, bb + ((kc + 1) & 1) * 2048, 4, 320, lane);
            WAITV(8);            // chunk kc landed; kc+1 in flight
        } else {
            WAITV(0);
        }
        const __half* pa = ab + (kc & 1) * 2048;
        const __half* pb = bb + (kc & 1) * 2048;
        half8 ah[4], bh[4];
        #pragma unroll
        for (int mt = 0; mt < 4; ++mt) ah[mt] = *(const half8*)(pa + (mt * 16 + lrow) * 32 + swz);
        #pragma unroll
        for (int nt = 0; nt < 4; ++nt) bh[nt] = *(const half8*)(pb + (nt * 16 + lrow) * 32 + swz);
        #pragma unroll
        for (int mt = 0; mt < 4; ++mt)
            #pragma unroll
            for (int nt = 0; nt < 4; ++nt)
                acc[mt][nt] = __builtin_amdgcn_mfma_f32_16x16x32_f16(
                    ah[mt], bh[nt], acc[mt][nt], 0, 0, 0);
    }

    if (epi == 2) {
        #pragma unroll
        for (int mt = 0; mt < 4; ++mt)
            #pragma unroll
            for (int nt = 0; nt < 4; ++nt)
                #pragma unroll
                for (int r = 0; r < 4; ++r) {
                    const int row = row_base + mt * 16 + quad * 4 + r;
                    const int col = col_base + nt * 16 + lrow;
                    hWT[(long)row * 8192 + col] = __float2half(acc[mt][nt][r]);
                }
    } else {
        #pragma unroll
        for (int mt = 0; mt < 4; ++mt)
            #pragma unroll
            for (int nt = 0; nt < 4; ++nt)
                #pragma unroll
                for (int r = 0; r < 4; ++r) {
                    const int row = row_base + mt * 16 + quad * 4 + r;
                    const int col = col_base + nt * 16 + lrow;
                    const float val = acc[mt][nt][r] + bqk[col];
                    const long idx = (long)row * 320 + (col >> 1);
                    if (col & 1) Ko[idx] = __float2half(val);
                    else         Qo[idx] = __float2half(val);
                }
    }
}

// ---------------------------------------------------------------------------
// fused_attn v4 (R19, passed): 512 thr (8 waves), grid 256, batch = bid&7.
// Phase A: P = 0.125 * Q @ K^T. Wave w owns at-cols [w*128, (w+1)*128) as
//   two 64-col groups; stages its own 64x32 K chunk into a wave-private
//   LDS dbuf (global_load_lds, counted vmcnt(4), no barriers). Q staged
//   once in LDS, block-XOR swizzled (conflict-free reads).
// Phase B: exact 171st-largest per row (2-pass radix, wave-private hist)
//   + softmax, in LDS; 4 rows/wave, no barriers inside.
// Phase C: out = attn @ hW_b + bias. Wave -> (q4 = w&3: 80 cols,
//   kh = w>>2: k-half); stages its own 80x32 hW chunk (vmcnt(5));
//   A-frags from P. f32 k-split reduction aliases P.
// ---------------------------------------------------------------------------
__global__ __launch_bounds__(512, 2) void fused_attn(
    const __half* __restrict__ Q, const __half* __restrict__ Kmat,
    const __half* __restrict__ hWT, const float* __restrict__ bias,
    float* __restrict__ out)
{
    __shared__ __half smem[77824];   // 155648 B
    __half* const P  = smem;         // 32768 halfs: 32x1024, idx ^= (row&7)<<3
    __half* const S  = smem + 32768; // 40960-half multiplex region
    __half* const QL = S;            // phase A: 10240 halfs (32x320, blk-swz)
    __half* const KB = S + 10240;    // phase A: 8 waves x 4096 halfs dbuf
    __half* const WB = S;            // phase C: 8 waves x 5120 halfs dbuf
    int (*const hist)[256] = (int(*)[256])(smem + 73728);  // 8 KB

    const int tid  = threadIdx.x;
    const int lane = tid & 63;
    const int wave = tid >> 6;       // 0..7
    const int lrow = lane & 15;
    const int quad = lane >> 4;
    const int swz  = (quad ^ ((lrow >> 1) & 3)) * 8;

    const int b  = blockIdx.x & 7;          // batch -> XCD affinity
    const int r0 = (blockIdx.x >> 3) * 32;  // query-row base

    const __half* Qb = Q    + (long)(b * 1024 + r0) * 320;
    const __half* Kb = Kmat + (long)b * 327680;
    const __half* Wb = hWT  + (long)b * 1024;

    // ---- stage Q (32x320) into QL, 8-half blocks XOR-swizzled by row&7 ----
    for (int i = wave; i < 20; i += 8) {
        const int s   = i * 64 + lane;       // slot 0..1279
        const int row = s / 40;
        const int cb  = s % 40;
        const int gb  = cb ^ (row & 7);      // global block held at this slot
        const __half* src = Qb + (long)row * 320 + gb * 8;
        __builtin_amdgcn_global_load_lds(
            (const __attribute__((address_space(1))) unsigned int*)src,
            (__attribute__((address_space(3))) unsigned int*)(QL + i * 512),
            16, 0, 0);
    }
    __half* const kb0 = KB + wave * 4096;    // this wave's K dbuf (2x2048)
    stage_wave(Kb + (long)(wave * 128) * 320, kb0, 4, 320, lane);  // r=0
    __syncthreads();   // barrier 1: Q + first K chunk visible

    // ---------------- Phase A: P = 0.125 * Q @ K^T ----------------
    #pragma unroll
    for (int cg = 0; cg < 2; ++cg) {
        f32x4 acc[4][2];
        #pragma unroll
        for (int i = 0; i < 4; ++i)
            #pragma unroll
            for (int j = 0; j < 2; ++j) acc[i][j] = (f32x4){0.f, 0.f, 0.f, 0.f};

        for (int kc = 0; kc < 10; ++kc) {
            const int r = cg * 10 + kc;
            if (r + 1 < 20) {
                const int cg1 = (r + 1) / 10, kc1 = (r + 1) % 10;
                stage_wave(Kb + (long)(wave * 128 + cg1 * 64) * 320 + kc1 * 32,
                           kb0 + ((r + 1) & 1) * 2048, 4, 320, lane);
                WAITV(4);          // chunk r landed; chunk r+1 in flight
            } else {
                WAITV(0);
            }
            const __half* kt = kb0 + (r & 1) * 2048;
            const int gbq = kc * 4 + quad;   // global 8-half block of Q
            half8 ah[2], bh[4];
            #pragma unroll
            for (int mi = 0; mi < 2; ++mi)
                ah[mi] = *(const half8*)&QL[(mi * 16 + lrow) * 320
                                            + (gbq ^ (lrow & 7)) * 8];
            #pragma unroll
            for (int cb = 0; cb < 4; ++cb)
                bh[cb] = *(const half8*)(kt + (cb * 16 + lrow) * 32 + swz);
            #pragma unroll
            for (int cb = 0; cb < 4; ++cb)
                #pragma unroll
                for (int mi = 0; mi < 2; ++mi)
                    acc[cb][mi] = __builtin_amdgcn_mfma_f32_16x16x32_f16(
                        ah[mi], bh[cb], acc[cb][mi], 0, 0, 0);
        }
        #pragma unroll
        for (int cb = 0; cb < 4; ++cb)
            #pragma unroll
            for (int mi = 0; mi < 2; ++mi)
                #pragma unroll
                for (int rr = 0; rr < 4; ++rr) {
                    const int row = mi * 16 + quad * 4 + rr;
                    const int col = wave * 128 + cg * 64 + cb * 16 + lrow;
                    P[((row << 10) + col) ^ ((row & 7) << 3)] =
                        __float2half(0.125f * acc[cb][mi][rr]);
                }
    }
    __syncthreads();   // barrier 2: P complete; KB/QL dead

    // ---- prefetch this wave's first hW chunk (lands during phase B) ----
    const int q4 = wave & 3;     // col quarter: 80 out-cols
    const int kh = wave >> 2;    // k-half
    __half* const wb0 = WB + wave * 5120;     // dbuf 2x2560
    const __half* Wbase = Wb + (long)(q4 * 80) * 8192 + kh * 512;
    stage_wave(Wbase, wb0, 5, 8192, lane);

    // ---------------- Phase B: topk + softmax (wave-private) ----------------
    #pragma unroll
    for (int j = 0; j < 4; ++j) {
        const int row  = wave * 4 + j;
        const int key8 = (row & 7) << 3;
        const int base = (row << 10) + lane * 16;

        unsigned short vs[16];
        *(uint4*)&vs[0] = *(const uint4*)&P[base ^ key8];
        *(uint4*)&vs[8] = *(const uint4*)&P[(base + 8) ^ key8];

        unsigned key[16];
        #pragma unroll
        for (int i = 0; i < 16; ++i) {
            const unsigned u = vs[i];
            key[i] = (u & 0x8000u) ? ((~u) & 0xFFFFu) : (u | 0x8000u);
        }

        unsigned prefix = 0, pmask = 0;
        int kk = 171;

        #pragma unroll
        for (int pass = 0; pass < 2; ++pass) {
            const int shift = 8 - 8 * pass;
            *(int4*)&hist[wave][lane * 4] = make_int4(0, 0, 0, 0);
            #pragma unroll
            for (int i = 0; i < 16; ++i) {
                if ((key[i] & pmask) == prefix)
                    atomicAdd(&hist[wave][(key[i] >> shift) & 255], 1);
            }
            const int4 hh = *(const int4*)&hist[wave][lane * 4];
            const int s = hh.x + hh.y + hh.z + hh.w;
            int suf = s;
            #pragma unroll
            for (int off = 1; off < 64; off <<= 1) {
                const int o = __shfl_down(suf, off);
                if (lane + off < 64) suf += o;
            }
            const int cgt3 = suf - s;
            const int cgt2 = cgt3 + hh.w;
            const int cgt1 = cgt2 + hh.z;
            const int cgt0 = cgt1 + hh.y;
            int pick = 0x7FFFFFFF;
            if (cgt3 < kk && kk <= cgt3 + hh.w) pick = ((4 * lane + 3) << 16) | (kk - cgt3);
            if (cgt2 < kk && kk <= cgt2 + hh.z) pick = ((4 * lane + 2) << 16) | (kk - cgt2);
            if (cgt1 < kk && kk <= cgt1 + hh.y) pick = ((4 * lane + 1) << 16) | (kk - cgt1);
            if (cgt0 < kk && kk <= cgt0 + hh.x) pick = ((4 * lane + 0) << 16) | (kk - cgt0);
            #pragma unroll
            for (int off = 32; off > 0; off >>= 1) pick = min(pick, __shfl_xor(pick, off));
            const unsigned digit = (unsigned)(pick >> 16);
            kk = pick & 0xFFFF;
            prefix |= digit << shift;
            pmask  |= 0xFFu << shift;
        }

        const unsigned short tu = (prefix & 0x8000u) ? (unsigned short)(prefix & 0x7FFFu)
                                                     : (unsigned short)((~prefix) & 0xFFFFu);
        const float thr = __half2float(__ushort_as_half(tu));

        float lg[16];
        float mx = -3.4e38f;
        #pragma unroll
        for (int i = 0; i < 16; ++i) {
            const float v = __half2float(__ushort_as_half(vs[i]));
            const float a = (v < thr) ? -1e-7f : v;
            lg[i] = a * (1.0f / 0.3f);
            mx = fmaxf(mx, lg[i]);
        }
        #pragma unroll
        for (int off = 32; off > 0; off >>= 1) mx = fmaxf(mx, __shfl_xor(mx, off));

        float e[16];
        float sum = 0.f;
        #pragma unroll
        for (int i = 0; i < 16; ++i) { e[i] = __expf(lg[i] - mx); sum += e[i]; }
        #pragma unroll
        for (int off = 32; off > 0; off >>= 1) sum += __shfl_xor(sum, off);
        const float inv = 1.0f / sum;

        unsigned short os[16];
        #pragma unroll
        for (int i = 0; i < 16; ++i) os[i] = __half_as_ushort(__float2half(e[i] * inv));
        *(uint4*)&P[base ^ key8]       = *(const uint4*)&os[0];
        *(uint4*)&P[(base + 8) ^ key8] = *(const uint4*)&os[8];
    }
    __syncthreads();   // barrier 3: attn in P; W chunk 0 already landed

    // ---------------- Phase C: out = P @ hW_b + bias ----------------
    f32x4 acc4[5][2];
    #pragma unroll
    for (int i = 0; i < 5; ++i)
        #pragma unroll
        for (int j = 0; j < 2; ++j) acc4[i][j] = (f32x4){0.f, 0.f, 0.f, 0.f};

    for (int t = 0; t < 16; ++t) {
        if (t + 1 < 16) {
            stage_wave(Wbase + (t + 1) * 32, wb0 + ((t + 1) & 1) * 2560,
                       5, 8192, lane);
            WAITV(5);          // chunk t landed; chunk t+1 in flight
        } else {
            WAITV(0);
        }
        const __half* T = wb0 + (t & 1) * 2560;
        const int kk = kh * 512 + t * 32 + quad * 8;
        half8 ah[2], bh[5];
        #pragma unroll
        for (int mi = 0; mi < 2; ++mi) {
            const int row = mi * 16 + lrow;
            ah[mi] = *(const half8*)&P[((row << 10) + kk) ^ ((row & 7) << 3)];
        }
        #pragma unroll
        for (int cf = 0; cf < 5; ++cf)
            bh[cf] = *(const half8*)(T + (cf * 16 + lrow) * 32 + swz);
        #pragma unroll
        for (int cf = 0; cf < 5; ++cf)
            #pragma unroll
            for (int mi = 0; mi < 2; ++mi)
                acc4[cf][mi] = __builtin_amdgcn_mfma_f32_16x16x32_f16(
                    ah[mi], bh[cf], acc4[cf][mi], 0, 0, 0);
    }

    __syncthreads();   // barrier 4: all P reads done; P region now dead
    float* const red = (float*)P;    // 32 x 320 f32 = 40 KB, aliases P
    if (kh == 1) {
        #pragma unroll
        for (int cf = 0; cf < 5; ++cf)
            #pragma unroll
            for (int mi = 0; mi < 2; ++mi)
                #pragma unroll
                for (int rr = 0; rr < 4; ++rr)
                    red[(mi * 16 + quad * 4 + rr) * 320 + q4 * 80 + cf * 16 + lrow] =
                        acc4[cf][mi][rr];
    }
    __syncthreads();   // barrier 5
    if (kh == 0) {
        #pragma unroll
        for (int cf = 0; cf < 5; ++cf)
            #pragma unroll
            for (int mi = 0; mi < 2; ++mi)
                #pragma unroll
                for (int rr = 0; rr < 4; ++rr) {
                    const int row = mi * 16 + quad * 4 + rr;
                    const int col = q4 * 80 + cf * 16 + lrow;
                    out[(long)(b * 1024 + r0 + row) * 320 + col] =
                        acc4[cf][mi][rr] + red[row * 320 + col] + bias[col];
                }
    }
}

extern "C" void kernel_launch(void* const* d_in, const int* in_sizes, int n_in,
                              void* d_out, int out_size, void* d_ws, size_t ws_size,
                              hipStream_t stream) {
    (void)in_sizes; (void)n_in; (void)out_size; (void)ws_size;

    const float* h      = (const float*)d_in[0];  // 8x1024x320
    const float* Wqk    = (const float*)d_in[1];  // 320x640
    const float* bqk    = (const float*)d_in[2];  // 640
    const float* weight = (const float*)d_in[3];  // 320x320
    const float* bias   = (const float*)d_in[4];  // 320
    float* out = (float*)d_out;                   // 8192x320

    // workspace layout
    char* p = (char*)d_ws;
    __half* h16  = (__half*)p; p += 2621440L * 2;        // 5 MB
    __half* Q    = (__half*)p; p += 2621440L * 2;        // 5 MB
    __half* Kb   = (__half*)p; p += 2621440L * 2;        // 5 MB
    __half* WqkT = (__half*)p; p += 640L * 320 * 2;      // 400 KB
    __half* wTp  = (__half*)p; p += 384L * 320 * 2;      // padded to 384 rows
    __half* hWT  = (__half*)p; p += 384L * 8192 * 2;     // 6 MB (incl pad rows)

    // --- prep (1 launch): h->fp16, WqkT, wTp ---
    prep_all<<<2860, 256, 0, stream>>>(h, (ushort4*)h16, Wqk, WqkT, weight, wTp);

    // --- g1_wave: 1920 independent 64x64 wave-tiles (hWT + Q/K), 0 barriers ---
    g1_wave<<<480, 256, 0, stream>>>(h16, wTp, WqkT, hWT, Q, Kb, bqk);

    // --- fused G2 + topk/softmax + G4: wave-autonomous staging (R19) ---
    fused_attn<<<256, 512, 0, stream>>>(Q, Kb, hWT, bias, out);
}